// Round 1
// baseline (204.388 us; speedup 1.0000x reference)
//
#include <hip/hip_runtime.h>

#define NDIM 16
#define HID  64
#define NCLS 2
#define BB   16
#define TT   64
#define NN   400

// ---------------------------------------------------------------------------
// Kernel 1: per-(b,t) -> feats[b,t,0:64]
//   colsum[m] = sum_n adj[b,t,n,m]
//   y[d] = sum_m colsum[m] * x[b,t,m,d]   (d=0..15),  s = sum_m colsum[m]
//   feats[h] = (sum_d y[d]*Wp[d,h] + s*bp[h]) / N
// ---------------------------------------------------------------------------
__global__ __launch_bounds__(256) void feats_kernel(
    const float* __restrict__ x_seq,
    const float* __restrict__ adj_seq,
    const float* __restrict__ Wp,
    const float* __restrict__ bp,
    float* __restrict__ feats)
{
    const int bt = blockIdx.x;                 // 0 .. B*T-1
    const float* __restrict__ adj = adj_seq + (size_t)bt * NN * NN;
    const float* __restrict__ xbt = x_seq   + (size_t)bt * NN * NDIM;
    const int tid = threadIdx.x;

    __shared__ float4 cpart[2][100];
    __shared__ float  colsum[NN];
    __shared__ float  wred[4][17];
    __shared__ float  yf[17];

    // ---- Phase A: column sums of the 400x400 adj tile (coalesced float4) ----
    const int mq = tid & 127;   // float4 column group 0..127 (0..99 used)
    const int nr = tid >> 7;    // row parity 0/1
    if (mq < 100) {
        float4 cs = make_float4(0.f, 0.f, 0.f, 0.f);
        const float* base = adj + mq * 4;
        #pragma unroll 4
        for (int n = nr; n < NN; n += 2) {
            float4 v = *reinterpret_cast<const float4*>(base + (size_t)n * NN);
            cs.x += v.x; cs.y += v.y; cs.z += v.z; cs.w += v.w;
        }
        cpart[nr][mq] = cs;
    }
    __syncthreads();
    if (tid < 100) {
        float4 a = cpart[0][tid];
        float4 b = cpart[1][tid];
        colsum[tid * 4 + 0] = a.x + b.x;
        colsum[tid * 4 + 1] = a.y + b.y;
        colsum[tid * 4 + 2] = a.z + b.z;
        colsum[tid * 4 + 3] = a.w + b.w;
    }
    __syncthreads();

    // ---- Phase B: y[0:16] = colsum @ x, y[16] = sum(colsum) ----
    float y[17];
    #pragma unroll
    for (int i = 0; i < 17; i++) y[i] = 0.f;

    for (int m = tid; m < NN; m += 256) {
        float c = colsum[m];
        y[16] += c;
        const float4* xp = reinterpret_cast<const float4*>(xbt + m * NDIM);
        float4 v0 = xp[0], v1 = xp[1], v2 = xp[2], v3 = xp[3];
        y[0]  += c * v0.x;  y[1]  += c * v0.y;  y[2]  += c * v0.z;  y[3]  += c * v0.w;
        y[4]  += c * v1.x;  y[5]  += c * v1.y;  y[6]  += c * v1.z;  y[7]  += c * v1.w;
        y[8]  += c * v2.x;  y[9]  += c * v2.y;  y[10] += c * v2.z;  y[11] += c * v2.w;
        y[12] += c * v3.x;  y[13] += c * v3.y;  y[14] += c * v3.z;  y[15] += c * v3.w;
    }

    // wave-level butterfly reduce of 17 floats
    #pragma unroll
    for (int off = 32; off >= 1; off >>= 1) {
        #pragma unroll
        for (int i = 0; i < 17; i++) y[i] += __shfl_down(y[i], off, 64);
    }
    const int lane = tid & 63;
    const int wv   = tid >> 6;
    if (lane == 0) {
        #pragma unroll
        for (int i = 0; i < 17; i++) wred[wv][i] = y[i];
    }
    __syncthreads();
    if (tid < 17) {
        yf[tid] = wred[0][tid] + wred[1][tid] + wred[2][tid] + wred[3][tid];
    }
    __syncthreads();

    // ---- Phase C: feats[h] = (y @ Wp[:,h] + s*bp[h]) / N ----
    if (tid < HID) {
        float acc = 0.f;
        #pragma unroll
        for (int d = 0; d < NDIM; d++) acc += yf[d] * Wp[d * HID + tid];
        acc = (acc + yf[16] * bp[tid]) * (1.0f / (float)NN);
        feats[(size_t)bt * HID + tid] = acc;
    }
}

// ---------------------------------------------------------------------------
// Kernel 2: GRU over T=64 steps + classifier. One block per batch element.
// Thread j (0..191) owns gate-row j; W_ih/W_hh rows live in registers.
// ---------------------------------------------------------------------------
__global__ __launch_bounds__(192) void gru_kernel(
    const float* __restrict__ feats,
    const float* __restrict__ W_ih,
    const float* __restrict__ W_hh,
    const float* __restrict__ b_ih,
    const float* __restrict__ b_hh,
    const float* __restrict__ Wc,
    const float* __restrict__ bc,
    float* __restrict__ out)
{
    const int b = blockIdx.x;
    const int j = threadIdx.x;   // 0..191

    // load my two weight rows into registers (64 + 64 floats)
    float wih[HID], whh[HID];
    #pragma unroll
    for (int k4 = 0; k4 < HID / 4; k4++) {
        float4 a = *reinterpret_cast<const float4*>(W_ih + j * HID + k4 * 4);
        wih[4 * k4 + 0] = a.x; wih[4 * k4 + 1] = a.y;
        wih[4 * k4 + 2] = a.z; wih[4 * k4 + 3] = a.w;
        float4 h4 = *reinterpret_cast<const float4*>(W_hh + j * HID + k4 * 4);
        whh[4 * k4 + 0] = h4.x; whh[4 * k4 + 1] = h4.y;
        whh[4 * k4 + 2] = h4.z; whh[4 * k4 + 3] = h4.w;
    }
    const float bi = b_ih[j];
    const float bh = b_hh[j];

    __shared__ float hst[HID];
    __shared__ float fbuf[HID];
    __shared__ float rbuf[HID], zbuf[HID], inb[HID], hnb[HID];
    if (j < HID) hst[j] = 0.f;
    __syncthreads();

    const float* __restrict__ fb = feats + (size_t)b * TT * HID;
    for (int t = 0; t < TT; t++) {
        if (j < HID) fbuf[j] = fb[t * HID + j];
        __syncthreads();

        float gi = bi, gh = bh;
        #pragma unroll
        for (int k = 0; k < HID; k++) {
            gi += fbuf[k] * wih[k];
            gh += hst[k]  * whh[k];
        }

        if (j < 64) {
            rbuf[j] = 1.f / (1.f + expf(-(gi + gh)));
        } else if (j < 128) {
            zbuf[j - 64] = 1.f / (1.f + expf(-(gi + gh)));
        } else {
            inb[j - 128] = gi;
            hnb[j - 128] = gh;
        }
        __syncthreads();

        if (j < HID) {
            float nv = tanhf(inb[j] + rbuf[j] * hnb[j]);
            float z  = zbuf[j];
            hst[j] = (1.f - z) * nv + z * hst[j];
        }
        __syncthreads();
    }

    if (j < NCLS) {
        float acc = bc[j];
        #pragma unroll
        for (int h = 0; h < HID; h++) acc += hst[h] * Wc[h * NCLS + j];
        out[b * NCLS + j] = acc;
    }
}

// ---------------------------------------------------------------------------
extern "C" void kernel_launch(void* const* d_in, const int* in_sizes, int n_in,
                              void* d_out, int out_size, void* d_ws, size_t ws_size,
                              hipStream_t stream) {
    const float* x_seq   = (const float*)d_in[0];
    const float* adj_seq = (const float*)d_in[1];
    const float* Wp      = (const float*)d_in[2];
    const float* bp      = (const float*)d_in[3];
    const float* W_ih    = (const float*)d_in[4];
    const float* W_hh    = (const float*)d_in[5];
    const float* b_ih    = (const float*)d_in[6];
    const float* b_hh    = (const float*)d_in[7];
    const float* Wc      = (const float*)d_in[8];
    const float* bc      = (const float*)d_in[9];

    float* feats = (float*)d_ws;          // B*T*HID floats = 256 KiB
    float* out   = (float*)d_out;         // B*NCLS floats

    feats_kernel<<<BB * TT, 256, 0, stream>>>(x_seq, adj_seq, Wp, bp, feats);
    gru_kernel<<<BB, 192, 0, stream>>>(feats, W_ih, W_hh, b_ih, b_hh, Wc, bc, out);
}

// Round 2
// 174.622 us; speedup vs baseline: 1.1705x; 1.1705x over previous
//
#include <hip/hip_runtime.h>

#define NDIM 16
#define HID  64
#define G3   192   // 3*HID
#define NCLS 2
#define BB   16
#define TT   64
#define NN   400

// ---------------------------------------------------------------------------
// Kernel 1: per-(b,t) block (512 threads):
//   colsum[m] = sum_n adj[n,m]            (streaming, 4-row parity, unroll 8)
//   y[d]      = sum_m colsum[m]*x[m,d], y[16] = sum_m colsum[m]
//   feats[h]  = (y @ Wp[:,h] + y16*bp[h]) / N          (LDS only)
//   gi[j]     = b_ih[j] + sum_k feats[k]*W_ih[j,k]     -> ws (only output)
// ---------------------------------------------------------------------------
__global__ __launch_bounds__(512) void feats_gi_kernel(
    const float* __restrict__ x_seq,
    const float* __restrict__ adj_seq,
    const float* __restrict__ Wp,
    const float* __restrict__ bp,
    const float* __restrict__ W_ih,
    const float* __restrict__ b_ih,
    float* __restrict__ gi_out)
{
    const int bt = blockIdx.x;
    const float* __restrict__ adj = adj_seq + (size_t)bt * NN * NN;
    const float* __restrict__ xbt = x_seq   + (size_t)bt * NN * NDIM;
    const int tid = threadIdx.x;

    __shared__ float4 cpart[4][100];
    __shared__ float  colsum[NN];
    __shared__ float  wred[8][17];
    __shared__ float  yf[17];
    __shared__ float  ffin[HID];

    // ---- Phase A: column sums, 512 threads = 128 col-slots x 4 row-parities
    const int mq = tid & 127;   // float4 column group (0..99 used)
    const int nr = tid >> 7;    // row parity 0..3
    if (mq < 100) {
        float4 cs = make_float4(0.f, 0.f, 0.f, 0.f);
        const float* base = adj + mq * 4 + (size_t)nr * NN;
        #pragma unroll 8
        for (int i = 0; i < 100; i++) {   // rows nr, nr+4, ..., nr+396
            float4 v = *reinterpret_cast<const float4*>(base + (size_t)i * 4 * NN);
            cs.x += v.x; cs.y += v.y; cs.z += v.z; cs.w += v.w;
        }
        cpart[nr][mq] = cs;
    }
    __syncthreads();
    if (tid < 100) {
        float4 a = cpart[0][tid], b = cpart[1][tid];
        float4 c = cpart[2][tid], d = cpart[3][tid];
        colsum[tid * 4 + 0] = (a.x + b.x) + (c.x + d.x);
        colsum[tid * 4 + 1] = (a.y + b.y) + (c.y + d.y);
        colsum[tid * 4 + 2] = (a.z + b.z) + (c.z + d.z);
        colsum[tid * 4 + 3] = (a.w + b.w) + (c.w + d.w);
    }
    __syncthreads();

    // ---- Phase B: y[0:16] = colsum @ x, y[16] = sum(colsum); 400 threads, 1 m each
    float y[17];
    #pragma unroll
    for (int i = 0; i < 17; i++) y[i] = 0.f;
    if (tid < NN) {
        const int m = tid;
        float c = colsum[m];
        y[16] = c;
        const float4* xp = reinterpret_cast<const float4*>(xbt + m * NDIM);
        float4 v0 = xp[0], v1 = xp[1], v2 = xp[2], v3 = xp[3];
        y[0]  = c * v0.x;  y[1]  = c * v0.y;  y[2]  = c * v0.z;  y[3]  = c * v0.w;
        y[4]  = c * v1.x;  y[5]  = c * v1.y;  y[6]  = c * v1.z;  y[7]  = c * v1.w;
        y[8]  = c * v2.x;  y[9]  = c * v2.y;  y[10] = c * v2.z;  y[11] = c * v2.w;
        y[12] = c * v3.x;  y[13] = c * v3.y;  y[14] = c * v3.z;  y[15] = c * v3.w;
    }
    #pragma unroll
    for (int off = 32; off >= 1; off >>= 1) {
        #pragma unroll
        for (int i = 0; i < 17; i++) y[i] += __shfl_down(y[i], off, 64);
    }
    const int lane = tid & 63;
    const int wv   = tid >> 6;      // 0..7
    if (lane == 0) {
        #pragma unroll
        for (int i = 0; i < 17; i++) wred[wv][i] = y[i];
    }
    __syncthreads();
    if (tid < 17) {
        float s = 0.f;
        #pragma unroll
        for (int w = 0; w < 8; w++) s += wred[w][tid];
        yf[tid] = s;
    }
    __syncthreads();

    // ---- Phase C: feats into LDS ----
    if (tid < HID) {
        float acc = 0.f;
        #pragma unroll
        for (int d = 0; d < NDIM; d++) acc += yf[d] * Wp[d * HID + tid];
        ffin[tid] = (acc + yf[16] * bp[tid]) * (1.0f / (float)NN);
    }
    __syncthreads();

    // ---- Phase D: gi = b_ih + feats @ W_ih.T  -> ws ----
    if (tid < G3) {
        const float4* wr = reinterpret_cast<const float4*>(W_ih + tid * HID);
        float acc = b_ih[tid];
        #pragma unroll
        for (int k4 = 0; k4 < HID / 4; k4++) {
            float4 w = wr[k4];
            acc += ffin[4 * k4 + 0] * w.x + ffin[4 * k4 + 1] * w.y
                 + ffin[4 * k4 + 2] * w.z + ffin[4 * k4 + 3] * w.w;
        }
        gi_out[(size_t)bt * G3 + tid] = acc;
    }
}

// ---------------------------------------------------------------------------
// Kernel 2: GRU recurrence (gh part only, gi precomputed) + classifier.
// One block per batch element, 192 threads, W_hh rows in registers.
// ---------------------------------------------------------------------------
__global__ __launch_bounds__(192) void gru_kernel(
    const float* __restrict__ gi_all,
    const float* __restrict__ W_hh,
    const float* __restrict__ b_hh,
    const float* __restrict__ Wc,
    const float* __restrict__ bc,
    float* __restrict__ out)
{
    const int b = blockIdx.x;
    const int j = threadIdx.x;   // 0..191, wave0=r, wave1=z, wave2=n

    float whh[HID];
    #pragma unroll
    for (int k4 = 0; k4 < HID / 4; k4++) {
        float4 w = *reinterpret_cast<const float4*>(W_hh + j * HID + 4 * k4);
        whh[4 * k4 + 0] = w.x; whh[4 * k4 + 1] = w.y;
        whh[4 * k4 + 2] = w.z; whh[4 * k4 + 3] = w.w;
    }
    const float bh = b_hh[j];

    __shared__ __align__(16) float hst[HID];
    __shared__ float rbuf[HID], zbuf[HID], inb[HID], hnb[HID];
    float hreg = 0.f;
    if (j < HID) hst[j] = 0.f;
    __syncthreads();

    const float* __restrict__ gi = gi_all + (size_t)b * TT * G3;
    float gcur = gi[j];

    for (int t = 0; t < TT; t++) {
        float gnext = (t + 1 < TT) ? gi[(t + 1) * G3 + j] : 0.f;  // prefetch

        float gh = bh;
        #pragma unroll
        for (int k4 = 0; k4 < HID / 4; k4++) {
            float4 h4 = *reinterpret_cast<const float4*>(hst + 4 * k4);
            gh += h4.x * whh[4 * k4 + 0] + h4.y * whh[4 * k4 + 1]
                + h4.z * whh[4 * k4 + 2] + h4.w * whh[4 * k4 + 3];
        }

        float g = gcur + gh;
        if (j < 64) {
            rbuf[j] = 1.f / (1.f + expf(-g));
        } else if (j < 128) {
            zbuf[j - 64] = 1.f / (1.f + expf(-g));
        } else {
            inb[j - 128] = gcur;   // i_n
            hnb[j - 128] = gh;     // h_n
        }
        __syncthreads();

        if (j < HID) {
            float nv = tanhf(inb[j] + rbuf[j] * hnb[j]);
            float z  = zbuf[j];
            hreg = (1.f - z) * nv + z * hreg;
            hst[j] = hreg;
        }
        __syncthreads();
        gcur = gnext;
    }

    if (j < NCLS) {
        float acc = bc[j];
        #pragma unroll
        for (int h = 0; h < HID; h++) acc += hst[h] * Wc[h * NCLS + j];
        out[b * NCLS + j] = acc;
    }
}

// ---------------------------------------------------------------------------
extern "C" void kernel_launch(void* const* d_in, const int* in_sizes, int n_in,
                              void* d_out, int out_size, void* d_ws, size_t ws_size,
                              hipStream_t stream) {
    const float* x_seq   = (const float*)d_in[0];
    const float* adj_seq = (const float*)d_in[1];
    const float* Wp      = (const float*)d_in[2];
    const float* bp      = (const float*)d_in[3];
    const float* W_ih    = (const float*)d_in[4];
    const float* W_hh    = (const float*)d_in[5];
    const float* b_ih    = (const float*)d_in[6];
    const float* b_hh    = (const float*)d_in[7];
    const float* Wc      = (const float*)d_in[8];
    const float* bc      = (const float*)d_in[9];

    float* gi  = (float*)d_ws;           // B*T*G3 floats = 768 KiB
    float* out = (float*)d_out;

    feats_gi_kernel<<<BB * TT, 512, 0, stream>>>(x_seq, adj_seq, Wp, bp,
                                                 W_ih, b_ih, gi);
    gru_kernel<<<BB, 192, 0, stream>>>(gi, W_hh, b_hh, Wc, bc, out);
}